// Round 8
// baseline (1341.750 us; speedup 1.0000x reference)
//
#include <hip/hip_runtime.h>
#include <hip/hip_bf16.h>
#include <math.h>

// Problem constants
#define TT 64
#define BB 256      // per-sequence batch
#define BT 512      // total batch (both sequences)
#define DD 300      // embedding dim
#define HH 512      // hidden
#define G4 2048     // 4*H
#define KX 320      // padded x-region K
#define KWP 1024    // WcatP physical K: [hi 512 | lo 512]
#define KC 64       // K chunk per LDS stage (gemm_x)
#define NCHX 5      // KX / KC

typedef __attribute__((ext_vector_type(8))) short short8v;
typedef __attribute__((ext_vector_type(4))) float f32x4;
typedef __attribute__((ext_vector_type(4))) unsigned short ushort4v;

__device__ __forceinline__ unsigned short f2bf(float f) {
    union { float f; unsigned int u; } v; v.f = f;
    unsigned int u = v.u;
    u += 0x7fffu + ((u >> 16) & 1u);   // round-to-nearest-even
    return (unsigned short)(u >> 16);
}
__device__ __forceinline__ float bf2f(unsigned short s) {
    union { unsigned int u; float f; } v; v.u = ((unsigned int)s) << 16;
    return v.f;
}
__device__ __forceinline__ float sigm(float x) { return 1.0f / (1.0f + __expf(-x)); }
__device__ __forceinline__ float tanh_f(float x) {
    float ax = fabsf(x);
    if (ax > 15.0f) return (x > 0.0f) ? 1.0f : -1.0f;
    float e = __expf(2.0f * ax);
    float t = 1.0f - 2.0f / (e + 1.0f);
    return (x >= 0.0f) ? t : -t;
}

// ---------------------------------------------------------------------------
// Prep: two weight layouts (verified R6/R7).
//  WcatP: row g'N = jt*64 + jj*4 + grp; K = [0,512)=Whh hi, [512,1024)=Whh lo.
//  WihP (gemm_x layout): row g'O = jt*64 + grp*16 + jj.
//  biasP[jt*64 + jj*4 + grp] = b_ih[g] + b_hh[g].
__global__ __launch_bounds__(256) void prep_w(const float* __restrict__ Wih,
                                              const float* __restrict__ Whh,
                                              const float* __restrict__ bih,
                                              const float* __restrict__ bhh,
                                              unsigned short* __restrict__ WcatP,
                                              unsigned short* __restrict__ WihP,
                                              float* __restrict__ biasP)
{
    const int gp = blockIdx.x;            // 0..2047
    const int jt = gp >> 6, r = gp & 63;
    const int grpO = r >> 4, jjO = r & 15;
    const int gO = grpO * 512 + jt * 16 + jjO;
    const int jjN = r >> 2, grpN = r & 3;
    const int gN = grpN * 512 + jt * 16 + jjN;

    for (int k = threadIdx.x; k < KWP; k += 256) {
        unsigned short v;
        if (k < HH) {
            v = f2bf(Whh[(size_t)gN * HH + k]);
        } else {
            float f = Whh[(size_t)gN * HH + (k - HH)];
            unsigned short hi = f2bf(f);
            v = f2bf(f - bf2f(hi));
        }
        WcatP[(size_t)gp * KWP + k] = v;
    }
    for (int k = threadIdx.x; k < KX; k += 256)
        WihP[(size_t)gp * KX + k] = (k < DD) ? f2bf(Wih[(size_t)gO * DD + k])
                                             : (unsigned short)0;
    if (threadIdx.x == 0) biasP[jt * 64 + jjO * 4 + grpO] = bih[gO] + bhh[gO];
}

// Prep: initial h (hi/lo bf16) and c into ping buffer 0.
__global__ __launch_bounds__(256) void prep_h(const float* __restrict__ h0a,
                                              const float* __restrict__ c0a,
                                              const float* __restrict__ h0b,
                                              const float* __restrict__ c0b,
                                              unsigned short* __restrict__ hhi,
                                              unsigned short* __restrict__ hlo,
                                              float* __restrict__ c)
{
    const int b = blockIdx.x; // 0..511
    for (int j = threadIdx.x; j < HH; j += 256) {
        float hv = (b < BB) ? h0a[b * HH + j] : h0b[(b - BB) * HH + j];
        float cv = (b < BB) ? c0a[b * HH + j] : c0b[(b - BB) * HH + j];
        unsigned short hi = f2bf(hv);
        hhi[b * HH + j] = hi;
        hlo[b * HH + j] = f2bf(hv - bf2f(hi));
        c[b * HH + j] = cv;
    }
}

// Pre-gather embeddings to bf16 (unchanged).
__global__ __launch_bounds__(256) void gather_x(const int* __restrict__ s1,
                                                const int* __restrict__ s2,
                                                const float* __restrict__ emb,
                                                unsigned short* __restrict__ Xbf)
{
    const int idx = blockIdx.x * 256 + threadIdx.x;   // TT*BT*40 threads
    const int row = idx / 40;
    const int seg = idx - row * 40;
    const int t = row >> 9;
    const int b = row & 511;
    const int tok = (b < BB) ? s1[t * BB + b] : s2[t * BB + (b - BB)];
    const int k = seg * 8;
    short8v v;
    if (k + 8 <= DD) {
        const float* e0 = emb + (size_t)tok * DD + k;
        float4 va = *(const float4*)e0;
        float4 vb = *(const float4*)(e0 + 4);
        v[0] = (short)f2bf(va.x); v[1] = (short)f2bf(va.y);
        v[2] = (short)f2bf(va.z); v[3] = (short)f2bf(va.w);
        v[4] = (short)f2bf(vb.x); v[5] = (short)f2bf(vb.y);
        v[6] = (short)f2bf(vb.z); v[7] = (short)f2bf(vb.w);
    } else {
        #pragma unroll
        for (int e = 0; e < 8; ++e) {
            int c = k + e;
            v[e] = (c < DD) ? (short)f2bf(emb[(size_t)tok * DD + c]) : (short)0;
        }
    }
    *(short8v*)&Xbf[(size_t)row * KX + k] = v;
}

// ---------------------------------------------------------------------------
// xprojP[m][g''] GEMM: g'' = jt*64 + jj*4 + grp. XCD-clustered mblk so the
// 32 n-tiles of one m-tile share an XCD's L2 (A reuse); nt stores so the
// 134 MB xprojP stream doesn't evict Xbf from LLC.
__global__ __launch_bounds__(256) void gemm_x(
    const unsigned short* __restrict__ Xbf,
    const unsigned short* __restrict__ WihP,
    unsigned short* __restrict__ xprojP)
{
    __shared__ __align__(16) unsigned short As[64 * 64];
    __shared__ __align__(16) unsigned short Bs[64 * 64];
    __shared__ __align__(16) float gbuf[64 * 65];

    const int tid = threadIdx.x;
    const int xcd   = blockIdx.x & 7;
    const int local = blockIdx.x >> 3;          // 0..2047
    const int mblk  = xcd * 64 + (local >> 5);  // 0..511 (64 m-tiles per XCD)
    const int nblk  = local & 31;

    const int lane = tid & 63;
    const int w = tid >> 6;
    const int wr = w >> 1, wc = w & 1;
    const int r16 = lane & 15;
    const int kg8 = lane >> 4;
    const int sl8 = lane >> 3;
    const int gd  = lane & 7;

    f32x4 acc[2][2] = {};

    auto load_chunk = [&](int ch, short8v* va, short8v* vb) {
        const int k0 = ch * KC;
        #pragma unroll
        for (int s = 0; s < 2; ++s) {
            const int r = w * 16 + s * 8 + sl8;
            va[s] = *(const short8v*)(Xbf + (size_t)(mblk * 64 + r) * KX + k0 + gd * 8);
            vb[s] = *(const short8v*)(WihP + (size_t)(nblk * 64 + r) * KX + k0 + gd * 8);
        }
    };
    auto write_chunk = [&](const short8v* va, const short8v* vb) {
        #pragma unroll
        for (int s = 0; s < 2; ++s) {
            const int r = w * 16 + s * 8 + sl8;
            const int g = (gd ^ sl8) << 3;
            *(short8v*)&As[r * 64 + g] = va[s];
            *(short8v*)&Bs[r * 64 + g] = vb[s];
        }
    };
    auto lidx = [&](int r, int ko) { return r * 64 + ((((ko) >> 3) ^ (r & 7)) << 3); };

    short8v va[2], vb[2], na[2], nb[2];
    load_chunk(0, va, vb);
    for (int ch = 0; ch < NCHX; ++ch) {
        write_chunk(va, vb);
        if (ch + 1 < NCHX) load_chunk(ch + 1, na, nb);
        __syncthreads();
        #pragma unroll
        for (int ks = 0; ks < KC; ks += 32) {
            const int ko = ks + kg8 * 8;
            short8v a0 = *(const short8v*)&As[lidx(32 * wr + r16,      ko)];
            short8v a1 = *(const short8v*)&As[lidx(32 * wr + 16 + r16, ko)];
            short8v b0 = *(const short8v*)&Bs[lidx(32 * wc + r16,      ko)];
            short8v b1 = *(const short8v*)&Bs[lidx(32 * wc + 16 + r16, ko)];
            acc[0][0] = __builtin_amdgcn_mfma_f32_16x16x32_bf16(a0, b0, acc[0][0], 0, 0, 0);
            acc[0][1] = __builtin_amdgcn_mfma_f32_16x16x32_bf16(a0, b1, acc[0][1], 0, 0, 0);
            acc[1][0] = __builtin_amdgcn_mfma_f32_16x16x32_bf16(a1, b0, acc[1][0], 0, 0, 0);
            acc[1][1] = __builtin_amdgcn_mfma_f32_16x16x32_bf16(a1, b1, acc[1][1], 0, 0, 0);
        }
        __syncthreads();
        #pragma unroll
        for (int s = 0; s < 2; ++s) { va[s] = na[s]; vb[s] = nb[s]; }
    }

    #pragma unroll
    for (int i = 0; i < 2; ++i)
        #pragma unroll
        for (int j = 0; j < 2; ++j)
            #pragma unroll
            for (int r = 0; r < 4; ++r) {
                int grow = (2 * wr + i) * 16 + kg8 * 4 + r;
                int gcol = (2 * wc + j) * 16 + r16;
                gbuf[grow * 65 + gcol] = acc[i][j][r];
            }
    __syncthreads();

    const int jj = tid & 15;
    const int row0 = tid >> 4;
    #pragma unroll
    for (int u = 0; u < 4; ++u) {
        int row = row0 + 16 * u;
        size_t m = (size_t)(mblk * 64 + row);
        ushort4v o;
        o[0] = f2bf(gbuf[row * 65 +      jj]);
        o[1] = f2bf(gbuf[row * 65 + 16 + jj]);
        o[2] = f2bf(gbuf[row * 65 + 32 + jj]);
        o[3] = f2bf(gbuf[row * 65 + 48 + jj]);
        __builtin_nontemporal_store(o, (ushort4v*)&xprojP[m * G4 + nblk * 64 + jj * 4]);
    }
}

// ---------------------------------------------------------------------------
// One LSTM timestep (per-step launch, HW inter-kernel sync). W fragments
// loaded into VGPRs at entry (no LDS B-staging, no K-loop barriers); h read
// per-lane direct from global (cached). Block decode packs (all bx, 4 jt)
// per XCD: per-XCD unique traffic = 512 KB W + 1 MB h per step.
#define MF(a, b, c) __builtin_amdgcn_mfma_f32_16x16x32_bf16(a, b, c, 0, 0, 0)

__global__ __launch_bounds__(256, 1) void lstm_step(
    const unsigned short* __restrict__ WcatP,
    const float* __restrict__ biasP,
    const unsigned short* __restrict__ xprojP,
    const unsigned short* __restrict__ hhi_in,
    const unsigned short* __restrict__ hlo_in,
    const float* __restrict__ c_in,
    unsigned short* __restrict__ hhi_out,
    unsigned short* __restrict__ hlo_out,
    float* __restrict__ c_out,
    int t)
{
    __shared__ __align__(16) float gbuf[64 * 68];   // 17408 B

    const int tid = threadIdx.x;
    const int bid = blockIdx.x;
    const int xcd = bid & 7;
    const int idx = bid >> 3;              // 0..31
    const int jt  = xcd + (idx & 3) * 8;   // 4 jt values per XCD -> W L2 reuse
    const int bx  = idx >> 2;              // 0..7

    const int lane = tid & 63;
    const int w = tid >> 6;
    const int wr = w >> 1, wc = w & 1;
    const int r16 = lane & 15;
    const int kg8 = lane >> 4;

    // ---- W fragments -> VGPRs (one-time, ~256 VGPR), [group][ks][colblock] --
    short8v whi[8][2][2], wlo[8][2][2];
    {
        const unsigned short* b0 = WcatP + (size_t)(jt * 64 + 32 * wc + r16) * KWP + kg8 * 8;
        const unsigned short* b1 = b0 + 16 * KWP;
        #pragma unroll
        for (int g = 0; g < 8; ++g)
            #pragma unroll
            for (int ks = 0; ks < 2; ++ks) {
                whi[g][ks][0] = *(const short8v*)(b0 + g * 64 + ks * 32);
                whi[g][ks][1] = *(const short8v*)(b1 + g * 64 + ks * 32);
                wlo[g][ks][0] = *(const short8v*)(b0 + 512 + g * 64 + ks * 32);
                wlo[g][ks][1] = *(const short8v*)(b1 + 512 + g * 64 + ks * 32);
            }
    }

    // ---- epilogue prefetch ----
    const int jj = tid & 15;
    const int row0 = tid >> 4;
    const f32x4 bp = *(const f32x4*)&biasP[jt * 64 + jj * 4];
    ushort4v xp[4]; float cp[4];
    #pragma unroll
    for (int u = 0; u < 4; ++u) {
        int batch = bx * 64 + row0 + 16 * u;
        xp[u] = __builtin_nontemporal_load(
            (const ushort4v*)&xprojP[((size_t)t * BT + batch) * G4 + jt * 64 + jj * 4]);
        cp[u] = c_in[batch * HH + jt * 16 + jj];
    }

    const int aoff0 = (bx * 64 + 32 * wr + r16) * HH + kg8 * 8;  // rowblock i=0
    const int aoff1 = aoff0 + 16 * HH;                           // rowblock i=1

    f32x4 acc[2][2] = {};
    #pragma unroll
    for (int g = 0; g < 8; ++g) {
        short8v ah[2][2], al[2][2];   // [ks][rowblock]
        #pragma unroll
        for (int ks = 0; ks < 2; ++ks) {
            ah[ks][0] = *(const short8v*)(hhi_in + aoff0 + g * 64 + ks * 32);
            ah[ks][1] = *(const short8v*)(hhi_in + aoff1 + g * 64 + ks * 32);
            al[ks][0] = *(const short8v*)(hlo_in + aoff0 + g * 64 + ks * 32);
            al[ks][1] = *(const short8v*)(hlo_in + aoff1 + g * 64 + ks * 32);
        }
        #pragma unroll
        for (int ks = 0; ks < 2; ++ks)
            #pragma unroll
            for (int i = 0; i < 2; ++i) {
                acc[i][0] = MF(ah[ks][i], whi[g][ks][0], acc[i][0]);  // hi*Whi
                acc[i][1] = MF(ah[ks][i], whi[g][ks][1], acc[i][1]);
            }
        #pragma unroll
        for (int ks = 0; ks < 2; ++ks)
            #pragma unroll
            for (int i = 0; i < 2; ++i) {
                acc[i][0] = MF(al[ks][i], whi[g][ks][0], acc[i][0]);  // lo*Whi
                acc[i][1] = MF(al[ks][i], whi[g][ks][1], acc[i][1]);
            }
        #pragma unroll
        for (int ks = 0; ks < 2; ++ks)
            #pragma unroll
            for (int i = 0; i < 2; ++i) {
                acc[i][0] = MF(ah[ks][i], wlo[g][ks][0], acc[i][0]);  // hi*Wlo
                acc[i][1] = MF(ah[ks][i], wlo[g][ks][1], acc[i][1]);
            }
    }

    // ---- gate exchange through LDS ----
    #pragma unroll
    for (int i = 0; i < 2; ++i)
        #pragma unroll
        for (int j2 = 0; j2 < 2; ++j2)
            #pragma unroll
            for (int r = 0; r < 4; ++r)
                gbuf[((2 * wr + i) * 16 + kg8 * 4 + r) * 68 + 32 * wc + 16 * j2 + r16]
                    = acc[i][j2][r];
    __syncthreads();

    // ---- cell update ----
    #pragma unroll
    for (int u = 0; u < 4; ++u) {
        int row = row0 + 16 * u;
        int batch = bx * 64 + row;
        f32x4 gv = *(const f32x4*)&gbuf[row * 68 + jj * 4];
        float gi = gv[0] + bp[0] + bf2f(xp[u][0]);
        float gf = gv[1] + bp[1] + bf2f(xp[u][1]);
        float gg = gv[2] + bp[2] + bf2f(xp[u][2]);
        float go = gv[3] + bp[3] + bf2f(xp[u][3]);
        float cn = sigm(gf) * cp[u] + sigm(gi) * tanh_f(gg);
        float hn = sigm(go) * tanh_f(cn);
        c_out[batch * HH + jt * 16 + jj] = cn;
        unsigned short hi = f2bf(hn);
        hhi_out[batch * HH + jt * 16 + jj] = hi;
        hlo_out[batch * HH + jt * 16 + jj] = f2bf(hn - bf2f(hi));
    }
}

// ---------------------------------------------------------------------------
__global__ __launch_bounds__(64) void finalize(const unsigned short* __restrict__ hhi,
                                               const unsigned short* __restrict__ hlo,
                                               float* __restrict__ out)
{
    const int b = blockIdx.x;       // 0..255
    const int lane = threadIdx.x;   // 64
    float s = 0.0f;
    for (int j = lane; j < HH; j += 64) {
        float ha = bf2f(hhi[b * HH + j]) + bf2f(hlo[b * HH + j]);
        float hb = bf2f(hhi[(b + BB) * HH + j]) + bf2f(hlo[(b + BB) * HH + j]);
        s += fabsf(ha - hb);
    }
    #pragma unroll
    for (int off = 32; off > 0; off >>= 1) s += __shfl_down(s, off);
    if (lane == 0) out[b] = expf(-s);
}

// ---------------------------------------------------------------------------
extern "C" void kernel_launch(void* const* d_in, const int* in_sizes, int n_in,
                              void* d_out, int out_size, void* d_ws, size_t ws_size,
                              hipStream_t stream)
{
    const int*   s1  = (const int*)d_in[0];
    const int*   s2  = (const int*)d_in[1];
    const float* emb = (const float*)d_in[2];
    const float* Wih = (const float*)d_in[3];
    const float* Whh = (const float*)d_in[4];
    const float* bih = (const float*)d_in[5];
    const float* bhh = (const float*)d_in[6];
    const float* h0a = (const float*)d_in[7];
    const float* c0a = (const float*)d_in[8];
    const float* h0b = (const float*)d_in[9];
    const float* c0b = (const float*)d_in[10];
    float* out = (float*)d_out;

    char* ws = (char*)d_ws;
    size_t off = 0;
    unsigned short* WcatP = (unsigned short*)(ws + off); off += (size_t)G4 * KWP * 2;   // 4 MB
    unsigned short* WihP  = (unsigned short*)(ws + off); off += (size_t)G4 * KX * 2;    // 1.3 MB
    float* biasP          = (float*)(ws + off);          off += (size_t)G4 * 4;
    unsigned short* hhi0  = (unsigned short*)(ws + off); off += (size_t)BT * HH * 2;
    unsigned short* hhi1  = (unsigned short*)(ws + off); off += (size_t)BT * HH * 2;
    unsigned short* hlo0  = (unsigned short*)(ws + off); off += (size_t)BT * HH * 2;
    unsigned short* hlo1  = (unsigned short*)(ws + off); off += (size_t)BT * HH * 2;
    float* cbuf0          = (float*)(ws + off);          off += (size_t)BT * HH * 4;
    float* cbuf1          = (float*)(ws + off);          off += (size_t)BT * HH * 4;
    unsigned short* Xbf   = (unsigned short*)(ws + off); off += (size_t)TT * BT * KX * 2; // 21 MB
    unsigned short* xprojP= (unsigned short*)(ws + off); off += (size_t)TT * BT * G4 * 2; // 134 MB

    prep_w<<<G4, 256, 0, stream>>>(Wih, Whh, bih, bhh, WcatP, WihP, biasP);
    prep_h<<<BT, 256, 0, stream>>>(h0a, c0a, h0b, c0b, hhi0, hlo0, cbuf0);
    gather_x<<<(TT * BT * 40) / 256, 256, 0, stream>>>(s1, s2, emb, Xbf);
    gemm_x<<<512 * 32, 256, 0, stream>>>(Xbf, WihP, xprojP);

    unsigned short* hhi[2] = { hhi0, hhi1 };
    unsigned short* hlo[2] = { hlo0, hlo1 };
    float*          cb[2]  = { cbuf0, cbuf1 };
    for (int t = 0; t < TT; ++t) {
        int pi = t & 1, po = pi ^ 1;
        lstm_step<<<256, 256, 0, stream>>>(WcatP, biasP, xprojP,
                                           hhi[pi], hlo[pi], cb[pi],
                                           hhi[po], hlo[po], cb[po], t);
    }
    // t=63 (odd) writes buffer 0
    finalize<<<BB, 64, 0, stream>>>(hhi0, hlo0, out);
}

// Round 9
// 1235.244 us; speedup vs baseline: 1.0862x; 1.0862x over previous
//
#include <hip/hip_runtime.h>
#include <hip/hip_bf16.h>
#include <math.h>

// Problem constants
#define TT 64
#define BB 256      // per-sequence batch
#define BT 512      // total batch (both sequences)
#define DD 300      // embedding dim
#define HH 512      // hidden
#define G4 2048     // 4*H
#define KX 320      // padded x-region K
#define KH 1536     // step K: [hi|lo|hi] x [Whi|Whi|Wlo]
#define KC 64       // K chunk (gemm_x)
#define NCHX 5      // KX / KC
#define KC2 128     // K chunk (lstm_step)
#define NCH2 12     // KH / KC2

typedef __attribute__((ext_vector_type(8))) short short8v;
typedef __attribute__((ext_vector_type(4))) float f32x4;
typedef __attribute__((ext_vector_type(4))) unsigned short ushort4v;

__device__ __forceinline__ unsigned short f2bf(float f) {
    union { float f; unsigned int u; } v; v.f = f;
    unsigned int u = v.u;
    u += 0x7fffu + ((u >> 16) & 1u);   // round-to-nearest-even
    return (unsigned short)(u >> 16);
}
__device__ __forceinline__ float bf2f(unsigned short s) {
    union { unsigned int u; float f; } v; v.u = ((unsigned int)s) << 16;
    return v.f;
}
__device__ __forceinline__ float sigm(float x) { return 1.0f / (1.0f + __expf(-x)); }
__device__ __forceinline__ float tanh_f(float x) {
    float ax = fabsf(x);
    if (ax > 15.0f) return (x > 0.0f) ? 1.0f : -1.0f;
    float e = __expf(2.0f * ax);
    float t = 1.0f - 2.0f / (e + 1.0f);
    return (x >= 0.0f) ? t : -t;
}

// ---------------------------------------------------------------------------
// Prep:
//  WcatP[g''][KH]: g'' = 4*j + gate (gate 0..3 = i,f,g,o), source g = gate*512+j.
//    K layout: [0,512)=Whh_hi, [512,1024)=Whh_hi, [1024,1536)=Whh_lo.
//  WihP (gemm_x layout, unchanged): row g'O = jt*64 + grp*16 + jj.
//  biasP[4*j + gate] = b_ih[g] + b_hh[g]  (same function as before).
__global__ __launch_bounds__(256) void prep_w(const float* __restrict__ Wih,
                                              const float* __restrict__ Whh,
                                              const float* __restrict__ bih,
                                              const float* __restrict__ bhh,
                                              unsigned short* __restrict__ WcatP,
                                              unsigned short* __restrict__ WihP,
                                              float* __restrict__ biasP)
{
    const int gp = blockIdx.x;            // 0..2047
    // new decode (WcatP): g'' = 4j + gate
    const int jN = gp >> 2, gateN = gp & 3;
    const int gN = gateN * 512 + jN;
    // old decode (WihP / biasP)
    const int jt = gp >> 6, r = gp & 63;
    const int grpO = r >> 4, jjO = r & 15;
    const int gO = grpO * 512 + jt * 16 + jjO;

    for (int k = threadIdx.x; k < KH; k += 256) {
        unsigned short v;
        if (k < 2 * HH) {
            v = f2bf(Whh[(size_t)gN * HH + (k & (HH - 1))]);     // hi (twice)
        } else {
            float f = Whh[(size_t)gN * HH + (k - 2 * HH)];
            unsigned short hi = f2bf(f);
            v = f2bf(f - bf2f(hi));                              // lo
        }
        WcatP[(size_t)gp * KH + k] = v;
    }
    for (int k = threadIdx.x; k < KX; k += 256)
        WihP[(size_t)gp * KX + k] = (k < DD) ? f2bf(Wih[(size_t)gO * DD + k])
                                             : (unsigned short)0;
    if (threadIdx.x == 0) biasP[jt * 64 + jjO * 4 + grpO] = bih[gO] + bhh[gO];
}

// Prep: initial h (hi/lo bf16) and c (single in-place buffer).
__global__ __launch_bounds__(256) void prep_h(const float* __restrict__ h0a,
                                              const float* __restrict__ c0a,
                                              const float* __restrict__ h0b,
                                              const float* __restrict__ c0b,
                                              unsigned short* __restrict__ hhi,
                                              unsigned short* __restrict__ hlo,
                                              float* __restrict__ c)
{
    const int b = blockIdx.x; // 0..511
    for (int j = threadIdx.x; j < HH; j += 256) {
        float hv = (b < BB) ? h0a[b * HH + j] : h0b[(b - BB) * HH + j];
        float cv = (b < BB) ? c0a[b * HH + j] : c0b[(b - BB) * HH + j];
        unsigned short hi = f2bf(hv);
        hhi[b * HH + j] = hi;
        hlo[b * HH + j] = f2bf(hv - bf2f(hi));
        c[b * HH + j] = cv;
    }
}

// Pre-gather embeddings to bf16 (unchanged, verified).
__global__ __launch_bounds__(256) void gather_x(const int* __restrict__ s1,
                                                const int* __restrict__ s2,
                                                const float* __restrict__ emb,
                                                unsigned short* __restrict__ Xbf)
{
    const int idx = blockIdx.x * 256 + threadIdx.x;   // TT*BT*40 threads
    const int row = idx / 40;
    const int seg = idx - row * 40;
    const int t = row >> 9;
    const int b = row & 511;
    const int tok = (b < BB) ? s1[t * BB + b] : s2[t * BB + (b - BB)];
    const int k = seg * 8;
    short8v v;
    if (k + 8 <= DD) {
        const float* e0 = emb + (size_t)tok * DD + k;
        float4 va = *(const float4*)e0;
        float4 vb = *(const float4*)(e0 + 4);
        v[0] = (short)f2bf(va.x); v[1] = (short)f2bf(va.y);
        v[2] = (short)f2bf(va.z); v[3] = (short)f2bf(va.w);
        v[4] = (short)f2bf(vb.x); v[5] = (short)f2bf(vb.y);
        v[6] = (short)f2bf(vb.z); v[7] = (short)f2bf(vb.w);
    } else {
        #pragma unroll
        for (int e = 0; e < 8; ++e) {
            int c = k + e;
            v[e] = (c < DD) ? (short)f2bf(emb[(size_t)tok * DD + c]) : (short)0;
        }
    }
    *(short8v*)&Xbf[(size_t)row * KX + k] = v;
}

// ---------------------------------------------------------------------------
// xprojP[m][g''] GEMM (unchanged from R8, verified): g'' = jt*64+jj*4+grp = 4j+gate.
__global__ __launch_bounds__(256) void gemm_x(
    const unsigned short* __restrict__ Xbf,
    const unsigned short* __restrict__ WihP,
    unsigned short* __restrict__ xprojP)
{
    __shared__ __align__(16) unsigned short As[64 * 64];
    __shared__ __align__(16) unsigned short Bs[64 * 64];
    __shared__ __align__(16) float gbuf[64 * 65];

    const int tid = threadIdx.x;
    const int xcd   = blockIdx.x & 7;
    const int local = blockIdx.x >> 3;
    const int mblk  = xcd * 64 + (local >> 5);
    const int nblk  = local & 31;

    const int lane = tid & 63;
    const int w = tid >> 6;
    const int wr = w >> 1, wc = w & 1;
    const int r16 = lane & 15;
    const int kg8 = lane >> 4;
    const int sl8 = lane >> 3;
    const int gd  = lane & 7;

    f32x4 acc[2][2] = {};

    auto load_chunk = [&](int ch, short8v* va, short8v* vb) {
        const int k0 = ch * KC;
        #pragma unroll
        for (int s = 0; s < 2; ++s) {
            const int r = w * 16 + s * 8 + sl8;
            va[s] = *(const short8v*)(Xbf + (size_t)(mblk * 64 + r) * KX + k0 + gd * 8);
            vb[s] = *(const short8v*)(WihP + (size_t)(nblk * 64 + r) * KX + k0 + gd * 8);
        }
    };
    auto write_chunk = [&](const short8v* va, const short8v* vb) {
        #pragma unroll
        for (int s = 0; s < 2; ++s) {
            const int r = w * 16 + s * 8 + sl8;
            const int g = (gd ^ sl8) << 3;
            *(short8v*)&As[r * 64 + g] = va[s];
            *(short8v*)&Bs[r * 64 + g] = vb[s];
        }
    };
    auto lidx = [&](int r, int ko) { return r * 64 + ((((ko) >> 3) ^ (r & 7)) << 3); };

    short8v va[2], vb[2], na[2], nb[2];
    load_chunk(0, va, vb);
    for (int ch = 0; ch < NCHX; ++ch) {
        write_chunk(va, vb);
        if (ch + 1 < NCHX) load_chunk(ch + 1, na, nb);
        __syncthreads();
        #pragma unroll
        for (int ks = 0; ks < KC; ks += 32) {
            const int ko = ks + kg8 * 8;
            short8v a0 = *(const short8v*)&As[lidx(32 * wr + r16,      ko)];
            short8v a1 = *(const short8v*)&As[lidx(32 * wr + 16 + r16, ko)];
            short8v b0 = *(const short8v*)&Bs[lidx(32 * wc + r16,      ko)];
            short8v b1 = *(const short8v*)&Bs[lidx(32 * wc + 16 + r16, ko)];
            acc[0][0] = __builtin_amdgcn_mfma_f32_16x16x32_bf16(a0, b0, acc[0][0], 0, 0, 0);
            acc[0][1] = __builtin_amdgcn_mfma_f32_16x16x32_bf16(a0, b1, acc[0][1], 0, 0, 0);
            acc[1][0] = __builtin_amdgcn_mfma_f32_16x16x32_bf16(a1, b0, acc[1][0], 0, 0, 0);
            acc[1][1] = __builtin_amdgcn_mfma_f32_16x16x32_bf16(a1, b1, acc[1][1], 0, 0, 0);
        }
        __syncthreads();
        #pragma unroll
        for (int s = 0; s < 2; ++s) { va[s] = na[s]; vb[s] = nb[s]; }
    }

    #pragma unroll
    for (int i = 0; i < 2; ++i)
        #pragma unroll
        for (int j = 0; j < 2; ++j)
            #pragma unroll
            for (int r = 0; r < 4; ++r) {
                int grow = (2 * wr + i) * 16 + kg8 * 4 + r;
                int gcol = (2 * wc + j) * 16 + r16;
                gbuf[grow * 65 + gcol] = acc[i][j][r];
            }
    __syncthreads();

    const int jj = tid & 15;
    const int row0 = tid >> 4;
    #pragma unroll
    for (int u = 0; u < 4; ++u) {
        int row = row0 + 16 * u;
        size_t m = (size_t)(mblk * 64 + row);
        ushort4v o;
        o[0] = f2bf(gbuf[row * 65 +      jj]);
        o[1] = f2bf(gbuf[row * 65 + 16 + jj]);
        o[2] = f2bf(gbuf[row * 65 + 32 + jj]);
        o[3] = f2bf(gbuf[row * 65 + 48 + jj]);
        __builtin_nontemporal_store(o, (ushort4v*)&xprojP[m * G4 + nblk * 64 + jj * 4]);
    }
}

// ---------------------------------------------------------------------------
// One LSTM timestep. Tile 64 batch x 32 gate-cols (= 8 j x 4 gates).
// 512 blocks x 128 thr (2 waves, 2 blocks/CU). W double-buffered through
// swizzled LDS; A (h hi/lo) per-lane direct from global with 1-chunk
// lookahead. 12 chunks of KC2=128, one barrier per chunk.
#define MF(a, b, c) __builtin_amdgcn_mfma_f32_16x16x32_bf16(a, b, c, 0, 0, 0)

__global__ __launch_bounds__(128) void lstm_step(
    const unsigned short* __restrict__ WcatP,
    const float* __restrict__ biasP,
    const unsigned short* __restrict__ xprojP,
    const unsigned short* __restrict__ hhi_in,
    const unsigned short* __restrict__ hlo_in,
    float* __restrict__ cbuf,
    unsigned short* __restrict__ hhi_out,
    unsigned short* __restrict__ hlo_out,
    int t)
{
    __shared__ __align__(16) unsigned short Bs0[32 * 128];  // 8 KB
    __shared__ __align__(16) unsigned short Bs1[32 * 128];  // 8 KB
    __shared__ __align__(16) float gbuf[64 * 36];           // 9 KB

    const int tid = threadIdx.x;
    const int bid = blockIdx.x;
    const int xcd   = bid & 7;
    const int local = bid >> 3;           // 0..63
    const int ct    = xcd * 8 + (local & 7);  // col tile 0..63 (8 per XCD)
    const int bx    = local >> 3;             // batch block 0..7

    const int lane = tid & 63;
    const int w = tid >> 6;               // wave 0/1 -> rows w*32..+32
    const int r16 = lane & 15;
    const int kg8 = lane >> 4;            // 0..3

    // W staging decode: thread covers 64B of one of 32 rows
    const int srow = tid >> 2;            // 0..31
    const int sq4  = tid & 3;
    const unsigned short* wbase =
        WcatP + (size_t)(ct * 32 + srow) * KH + sq4 * 32;

    // A row bases (per-lane direct loads)
    const int arow0 = (bx * 64 + w * 32 + r16) * HH;
    const int arow1 = arow0 + 16 * HH;

    f32x4 acc[2][2] = {};

    auto load_w = [&](int ch, short8v* wreg) {
        #pragma unroll
        for (int q = 0; q < 4; ++q)
            wreg[q] = *(const short8v*)(wbase + ch * KC2 + q * 8);
    };
    auto write_w = [&](unsigned short* Bs, const short8v* wreg) {
        #pragma unroll
        for (int q = 0; q < 4; ++q) {
            const int g16 = sq4 * 4 + q;
            const int gsw = g16 ^ (srow & 15);
            *(short8v*)&Bs[srow * 128 + gsw * 8] = wreg[q];
        }
    };
    auto load_a = [&](int ch, short8v* a) {
        const unsigned short* base = ((ch >> 2) == 1) ? hlo_in : hhi_in;
        const int koff = (ch & 3) * KC2 + kg8 * 8;
        #pragma unroll
        for (int ks = 0; ks < 4; ++ks) {
            a[ks]     = *(const short8v*)(base + arow0 + koff + ks * 32);
            a[4 + ks] = *(const short8v*)(base + arow1 + koff + ks * 32);
        }
    };
    auto compute = [&](const unsigned short* Bs, const short8v* a) {
        #pragma unroll
        for (int ks = 0; ks < 4; ++ks) {
            const int gsw = ((ks * 4 + kg8) ^ r16) * 8;
            short8v b0 = *(const short8v*)&Bs[r16 * 128 + gsw];
            short8v b1 = *(const short8v*)&Bs[(16 + r16) * 128 + gsw];
            acc[0][0] = MF(a[ks],     b0, acc[0][0]);
            acc[0][1] = MF(a[ks],     b1, acc[0][1]);
            acc[1][0] = MF(a[4 + ks], b0, acc[1][0]);
            acc[1][1] = MF(a[4 + ks], b1, acc[1][1]);
        }
    };

    short8v w0[4], w1[4], a0[8], a1[8];
    load_w(0, w0); load_a(0, a0);
    load_w(1, w1);

    // epilogue prefetch (independent; pipelines behind staging loads)
    const int jl   = tid & 7;             // local j 0..7
    const int row0 = tid >> 3;            // 0..15
    const int j    = ct * 8 + jl;
    const f32x4 bp = *(const f32x4*)&biasP[4 * j];
    ushort4v xp[4]; float cp[4];
    #pragma unroll
    for (int u = 0; u < 4; ++u) {
        int batch = bx * 64 + u * 16 + row0;
        xp[u] = *(const ushort4v*)&xprojP[((size_t)t * BT + batch) * G4 + 4 * j];
        cp[u] = cbuf[batch * HH + j];
    }

    write_w(Bs0, w0);
    __syncthreads();

    for (int ch = 0; ch < NCH2; ch += 2) {
        load_a(ch + 1, a1);
        if (ch + 2 < NCH2) load_w(ch + 2, w0);
        write_w(Bs1, w1);
        compute(Bs0, a0);                  // chunk ch
        __syncthreads();
        if (ch + 2 < NCH2) load_a(ch + 2, a0);
        if (ch + 3 < NCH2) load_w(ch + 3, w1);
        if (ch + 2 < NCH2) write_w(Bs0, w0);
        compute(Bs1, a1);                  // chunk ch+1
        __syncthreads();
    }

    // gate exchange: C row=(lane>>4)*4+reg, col=lane&15 (verified mapping)
    #pragma unroll
    for (int i = 0; i < 2; ++i)
        #pragma unroll
        for (int cb = 0; cb < 2; ++cb)
            #pragma unroll
            for (int r = 0; r < 4; ++r)
                gbuf[(w * 32 + i * 16 + kg8 * 4 + r) * 36 + cb * 16 + r16]
                    = acc[i][cb][r];
    __syncthreads();

    // cell update: 4 (b,j) pairs per thread
    #pragma unroll
    for (int u = 0; u < 4; ++u) {
        int row = u * 16 + row0;
        int batch = bx * 64 + row;
        f32x4 gv = *(const f32x4*)&gbuf[row * 36 + jl * 4];
        float gi = gv[0] + bp[0] + bf2f(xp[u][0]);
        float gf = gv[1] + bp[1] + bf2f(xp[u][1]);
        float gg = gv[2] + bp[2] + bf2f(xp[u][2]);
        float go = gv[3] + bp[3] + bf2f(xp[u][3]);
        float cn = sigm(gf) * cp[u] + sigm(gi) * tanh_f(gg);
        float hn = sigm(go) * tanh_f(cn);
        cbuf[batch * HH + j] = cn;
        unsigned short hi = f2bf(hn);
        hhi_out[batch * HH + j] = hi;
        hlo_out[batch * HH + j] = f2bf(hn - bf2f(hi));
    }
}

// ---------------------------------------------------------------------------
__global__ __launch_bounds__(64) void finalize(const unsigned short* __restrict__ hhi,
                                               const unsigned short* __restrict__ hlo,
                                               float* __restrict__ out)
{
    const int b = blockIdx.x;       // 0..255
    const int lane = threadIdx.x;   // 64
    float s = 0.0f;
    for (int j = lane; j < HH; j += 64) {
        float ha = bf2f(hhi[b * HH + j]) + bf2f(hlo[b * HH + j]);
        float hb = bf2f(hhi[(b + BB) * HH + j]) + bf2f(hlo[(b + BB) * HH + j]);
        s += fabsf(ha - hb);
    }
    #pragma unroll
    for (int off = 32; off > 0; off >>= 1) s += __shfl_down(s, off);
    if (lane == 0) out[b] = expf(-s);
}

// ---------------------------------------------------------------------------
extern "C" void kernel_launch(void* const* d_in, const int* in_sizes, int n_in,
                              void* d_out, int out_size, void* d_ws, size_t ws_size,
                              hipStream_t stream)
{
    const int*   s1  = (const int*)d_in[0];
    const int*   s2  = (const int*)d_in[1];
    const float* emb = (const float*)d_in[2];
    const float* Wih = (const float*)d_in[3];
    const float* Whh = (const float*)d_in[4];
    const float* bih = (const float*)d_in[5];
    const float* bhh = (const float*)d_in[6];
    const float* h0a = (const float*)d_in[7];
    const float* c0a = (const float*)d_in[8];
    const float* h0b = (const float*)d_in[9];
    const float* c0b = (const float*)d_in[10];
    float* out = (float*)d_out;

    char* ws = (char*)d_ws;
    size_t off = 0;
    unsigned short* WcatP = (unsigned short*)(ws + off); off += (size_t)G4 * KH * 2;   // 6.3 MB
    unsigned short* WihP  = (unsigned short*)(ws + off); off += (size_t)G4 * KX * 2;   // 1.3 MB
    float* biasP          = (float*)(ws + off);          off += (size_t)G4 * 4;
    unsigned short* hhi0  = (unsigned short*)(ws + off); off += (size_t)BT * HH * 2;
    unsigned short* hhi1  = (unsigned short*)(ws + off); off += (size_t)BT * HH * 2;
    unsigned short* hlo0  = (unsigned short*)(ws + off); off += (size_t)BT * HH * 2;
    unsigned short* hlo1  = (unsigned short*)(ws + off); off += (size_t)BT * HH * 2;
    float* cbuf           = (float*)(ws + off);          off += (size_t)BT * HH * 4;   // 1 MB
    unsigned short* Xbf   = (unsigned short*)(ws + off); off += (size_t)TT * BT * KX * 2; // 21 MB
    unsigned short* xprojP= (unsigned short*)(ws + off); off += (size_t)TT * BT * G4 * 2; // 134 MB

    prep_w<<<G4, 256, 0, stream>>>(Wih, Whh, bih, bhh, WcatP, WihP, biasP);
    prep_h<<<BT, 256, 0, stream>>>(h0a, c0a, h0b, c0b, hhi0, hlo0, cbuf);
    gather_x<<<(TT * BT * 40) / 256, 256, 0, stream>>>(s1, s2, emb, Xbf);
    gemm_x<<<512 * 32, 256, 0, stream>>>(Xbf, WihP, xprojP);

    unsigned short* hhi[2] = { hhi0, hhi1 };
    unsigned short* hlo[2] = { hlo0, hlo1 };
    for (int t = 0; t < TT; ++t) {
        int pi = t & 1, po = pi ^ 1;
        lstm_step<<<512, 128, 0, stream>>>(WcatP, biasP, xprojP,
                                           hhi[pi], hlo[pi], cbuf,
                                           hhi[po], hlo[po], t);
    }
    // t=63 (odd) writes buffer 0
    finalize<<<BB, 64, 0, stream>>>(hhi0, hlo0, out);
}

// Round 10
// 646.011 us; speedup vs baseline: 2.0770x; 1.9121x over previous
//
#include <hip/hip_runtime.h>
#include <hip/hip_bf16.h>
#include <math.h>

// Problem constants
#define TT 64
#define BB 256      // per-sequence batch
#define BT 512      // total batch (both sequences)
#define DD 300      // embedding dim
#define HH 512      // hidden
#define G4 2048     // 4*H
#define KX 320      // padded x-region K
#define KW 512      // physical W-hi K (read twice: A = [h_hi | h_lo])
#define KC 64       // K chunk per LDS stage
#define NCHX 5      // KX / KC
#define NCHH 16     // 1024 / KC (2-term: hi*Whi + lo*Whi)

typedef __attribute__((ext_vector_type(8))) short short8v;
typedef __attribute__((ext_vector_type(4))) float f32x4;
typedef __attribute__((ext_vector_type(4))) unsigned short ushort4v;

__device__ __forceinline__ unsigned short f2bf(float f) {
    union { float f; unsigned int u; } v; v.f = f;
    unsigned int u = v.u;
    u += 0x7fffu + ((u >> 16) & 1u);   // round-to-nearest-even
    return (unsigned short)(u >> 16);
}
__device__ __forceinline__ float bf2f(unsigned short s) {
    union { unsigned int u; float f; } v; v.u = ((unsigned int)s) << 16;
    return v.f;
}
__device__ __forceinline__ float sigm(float x) { return 1.0f / (1.0f + __expf(-x)); }
__device__ __forceinline__ float tanh_f(float x) {
    float ax = fabsf(x);
    if (ax > 15.0f) return (x > 0.0f) ? 1.0f : -1.0f;
    float e = __expf(2.0f * ax);
    float t = 1.0f - 2.0f / (e + 1.0f);
    return (x >= 0.0f) ? t : -t;
}

// ---------------------------------------------------------------------------
// Prep (R4-verified layouts, W truncated to the hi region only):
//  WcatP[g'][KW]: g' = jt*64 + grp*16 + jj  <->  gate g = grp*512 + jt*16 + jj
//  WihP[g'][KX]: bf16 W_ih rows (zero-padded 300..319)
//  biasP[jt*64 + jj*4 + grp] = b_ih[g] + b_hh[g]
__global__ __launch_bounds__(256) void prep_w(const float* __restrict__ Wih,
                                              const float* __restrict__ Whh,
                                              const float* __restrict__ bih,
                                              const float* __restrict__ bhh,
                                              unsigned short* __restrict__ WcatP,
                                              unsigned short* __restrict__ WihP,
                                              float* __restrict__ biasP)
{
    const int gp = blockIdx.x;            // g' 0..2047
    const int jt = gp >> 6, r = gp & 63;
    const int grp = r >> 4, jj = r & 15;
    const int g = grp * 512 + jt * 16 + jj;

    for (int k = threadIdx.x; k < KW; k += 256)
        WcatP[(size_t)gp * KW + k] = f2bf(Whh[(size_t)g * HH + k]);
    for (int k = threadIdx.x; k < KX; k += 256)
        WihP[(size_t)gp * KX + k] = (k < DD) ? f2bf(Wih[(size_t)g * DD + k])
                                             : (unsigned short)0;
    if (threadIdx.x == 0) biasP[jt * 64 + jj * 4 + grp] = bih[g] + bhh[g];
}

// Prep: initial h (hi/lo bf16) and c.
__global__ __launch_bounds__(256) void prep_h(const float* __restrict__ h0a,
                                              const float* __restrict__ c0a,
                                              const float* __restrict__ h0b,
                                              const float* __restrict__ c0b,
                                              unsigned short* __restrict__ hhi,
                                              unsigned short* __restrict__ hlo,
                                              float* __restrict__ c)
{
    const int b = blockIdx.x; // 0..511
    for (int j = threadIdx.x; j < HH; j += 256) {
        float hv = (b < BB) ? h0a[b * HH + j] : h0b[(b - BB) * HH + j];
        float cv = (b < BB) ? c0a[b * HH + j] : c0b[(b - BB) * HH + j];
        unsigned short hi = f2bf(hv);
        hhi[b * HH + j] = hi;
        hlo[b * HH + j] = f2bf(hv - bf2f(hi));
        c[b * HH + j] = cv;
    }
}

// Pre-gather embeddings to bf16: Xbf[t*512+b][0..KX) (zero-padded past DD).
__global__ __launch_bounds__(256) void gather_x(const int* __restrict__ s1,
                                                const int* __restrict__ s2,
                                                const float* __restrict__ emb,
                                                unsigned short* __restrict__ Xbf)
{
    const int idx = blockIdx.x * 256 + threadIdx.x;   // TT*BT*40 threads
    const int row = idx / 40;          // t*512 + b
    const int seg = idx - row * 40;    // 8-elem segment within 320
    const int t = row >> 9;
    const int b = row & 511;
    const int tok = (b < BB) ? s1[t * BB + b] : s2[t * BB + (b - BB)];
    const int k = seg * 8;
    short8v v;
    if (k + 8 <= DD) {
        const float* e0 = emb + (size_t)tok * DD + k;
        float4 va = *(const float4*)e0;
        float4 vb = *(const float4*)(e0 + 4);
        v[0] = (short)f2bf(va.x); v[1] = (short)f2bf(va.y);
        v[2] = (short)f2bf(va.z); v[3] = (short)f2bf(va.w);
        v[4] = (short)f2bf(vb.x); v[5] = (short)f2bf(vb.y);
        v[6] = (short)f2bf(vb.z); v[7] = (short)f2bf(vb.w);
    } else {
        #pragma unroll
        for (int e = 0; e < 8; ++e) {
            int c = k + e;
            v[e] = (c < DD) ? (short)f2bf(emb[(size_t)tok * DD + c]) : (short)0;
        }
    }
    *(short8v*)&Xbf[(size_t)row * KX + k] = v;
}

// ---------------------------------------------------------------------------
// xprojP[m][g''] GEMM (R8/R9-verified): g'' = jt*64 + jj*4 + grp.
// XCD-clustered mblk; nt stores keep the 134 MB stream out of LLC.
__global__ __launch_bounds__(256) void gemm_x(
    const unsigned short* __restrict__ Xbf,
    const unsigned short* __restrict__ WihP,
    unsigned short* __restrict__ xprojP)
{
    __shared__ __align__(16) unsigned short As[64 * 64];
    __shared__ __align__(16) unsigned short Bs[64 * 64];
    __shared__ __align__(16) float gbuf[64 * 65];

    const int tid = threadIdx.x;
    const int xcd   = blockIdx.x & 7;
    const int local = blockIdx.x >> 3;
    const int mblk  = xcd * 64 + (local >> 5);
    const int nblk  = local & 31;

    const int lane = tid & 63;
    const int w = tid >> 6;
    const int wr = w >> 1, wc = w & 1;
    const int r16 = lane & 15;
    const int kg8 = lane >> 4;
    const int sl8 = lane >> 3;
    const int gd  = lane & 7;

    f32x4 acc[2][2] = {};

    auto load_chunk = [&](int ch, short8v* va, short8v* vb) {
        const int k0 = ch * KC;
        #pragma unroll
        for (int s = 0; s < 2; ++s) {
            const int r = w * 16 + s * 8 + sl8;
            va[s] = *(const short8v*)(Xbf + (size_t)(mblk * 64 + r) * KX + k0 + gd * 8);
            vb[s] = *(const short8v*)(WihP + (size_t)(nblk * 64 + r) * KX + k0 + gd * 8);
        }
    };
    auto write_chunk = [&](const short8v* va, const short8v* vb) {
        #pragma unroll
        for (int s = 0; s < 2; ++s) {
            const int r = w * 16 + s * 8 + sl8;
            const int g = (gd ^ sl8) << 3;
            *(short8v*)&As[r * 64 + g] = va[s];
            *(short8v*)&Bs[r * 64 + g] = vb[s];
        }
    };
    auto lidx = [&](int r, int ko) { return r * 64 + ((((ko) >> 3) ^ (r & 7)) << 3); };

    short8v va[2], vb[2], na[2], nb[2];
    load_chunk(0, va, vb);
    for (int ch = 0; ch < NCHX; ++ch) {
        write_chunk(va, vb);
        if (ch + 1 < NCHX) load_chunk(ch + 1, na, nb);
        __syncthreads();
        #pragma unroll
        for (int ks = 0; ks < KC; ks += 32) {
            const int ko = ks + kg8 * 8;
            short8v a0 = *(const short8v*)&As[lidx(32 * wr + r16,      ko)];
            short8v a1 = *(const short8v*)&As[lidx(32 * wr + 16 + r16, ko)];
            short8v b0 = *(const short8v*)&Bs[lidx(32 * wc + r16,      ko)];
            short8v b1 = *(const short8v*)&Bs[lidx(32 * wc + 16 + r16, ko)];
            acc[0][0] = __builtin_amdgcn_mfma_f32_16x16x32_bf16(a0, b0, acc[0][0], 0, 0, 0);
            acc[0][1] = __builtin_amdgcn_mfma_f32_16x16x32_bf16(a0, b1, acc[0][1], 0, 0, 0);
            acc[1][0] = __builtin_amdgcn_mfma_f32_16x16x32_bf16(a1, b0, acc[1][0], 0, 0, 0);
            acc[1][1] = __builtin_amdgcn_mfma_f32_16x16x32_bf16(a1, b1, acc[1][1], 0, 0, 0);
        }
        __syncthreads();
        #pragma unroll
        for (int s = 0; s < 2; ++s) { va[s] = na[s]; vb[s] = nb[s]; }
    }

    #pragma unroll
    for (int i = 0; i < 2; ++i)
        #pragma unroll
        for (int j = 0; j < 2; ++j)
            #pragma unroll
            for (int r = 0; r < 4; ++r) {
                int grow = (2 * wr + i) * 16 + kg8 * 4 + r;
                int gcol = (2 * wc + j) * 16 + r16;
                gbuf[grow * 65 + gcol] = acc[i][j][r];
            }
    __syncthreads();

    const int jj = tid & 15;
    const int row0 = tid >> 4;
    #pragma unroll
    for (int u = 0; u < 4; ++u) {
        int row = row0 + 16 * u;
        size_t m = (size_t)(mblk * 64 + row);
        ushort4v o;
        o[0] = f2bf(gbuf[row * 65 +      jj]);
        o[1] = f2bf(gbuf[row * 65 + 16 + jj]);
        o[2] = f2bf(gbuf[row * 65 + 32 + jj]);
        o[3] = f2bf(gbuf[row * 65 + 48 + jj]);
        __builtin_nontemporal_store(o, (ushort4v*)&xprojP[m * G4 + nblk * 64 + jj * 4]);
    }
}

// ---------------------------------------------------------------------------
// One LSTM timestep (R4-verified structure), 2-term: A-K = [h_hi | h_lo],
// B reads the same W_hi slice for both halves (L2-hot second pass).
// 16 chunks of KC=64, double-buffered LDS, 64x64 tile, 256 blocks.
__global__ __launch_bounds__(256) void lstm_step(
    const unsigned short* __restrict__ WcatP,
    const float* __restrict__ biasP,
    const unsigned short* __restrict__ xprojP,
    const unsigned short* __restrict__ hhi_in,
    const unsigned short* __restrict__ hlo_in,
    float* __restrict__ cbuf,
    unsigned short* __restrict__ hhi_out,
    unsigned short* __restrict__ hlo_out,
    int t)
{
    __shared__ __align__(16) unsigned short As0[64 * 64], As1[64 * 64];
    __shared__ __align__(16) unsigned short Bs0[64 * 64], Bs1[64 * 64];
    __shared__ __align__(16) float gbuf[64 * 65];

    const int tid = threadIdx.x;
    const int bid = blockIdx.x;

    // XCD-aware decode: each XCD owns 4 contiguous jt tiles.
    const int xcd   = bid & 7;
    const int local = bid >> 3;
    const int bx    = local & 7;
    const int jt    = xcd * 4 + (local >> 3);

    const int lane = tid & 63;
    const int w = tid >> 6;
    const int wr = w >> 1, wc = w & 1;
    const int r16 = lane & 15;
    const int kg8 = lane >> 4;
    const int sl8 = lane >> 3;
    const int gd  = lane & 7;

    f32x4 acc[2][2] = {};

    auto load_chunk = [&](int ch, short8v* va, short8v* vb) {
        const int k0 = ch * KC;
        const unsigned short* abase = (k0 < HH)
            ? hhi_in + (size_t)(bx * 64) * HH + k0
            : hlo_in + (size_t)(bx * 64) * HH + (k0 - HH);
        const int kw = k0 & (HH - 1);      // W-hi slice re-read for lo half
        #pragma unroll
        for (int s = 0; s < 2; ++s) {
            const int r = w * 16 + s * 8 + sl8;
            va[s] = *(const short8v*)(abase + (size_t)r * HH + gd * 8);
            const int wrow = (r >> 4) * HH + jt * 16 + (r & 15);  // g' row
            vb[s] = *(const short8v*)(WcatP + (size_t)(jt * 64 + (r >> 4) * 16 + (r & 15)) * KW + kw + gd * 8);
        }
    };
    auto write_chunk = [&](unsigned short* A, unsigned short* B,
                           const short8v* va, const short8v* vb) {
        #pragma unroll
        for (int s = 0; s < 2; ++s) {
            const int r = w * 16 + s * 8 + sl8;
            const int g = (gd ^ sl8) << 3;     // r&7 == sl8
            *(short8v*)&A[r * 64 + g] = va[s];
            *(short8v*)&B[r * 64 + g] = vb[s];
        }
    };
    auto lidx = [&](int r, int ko) { return r * 64 + ((((ko) >> 3) ^ (r & 7)) << 3); };
    auto compute = [&](const unsigned short* A, const unsigned short* B) {
        #pragma unroll
        for (int ks = 0; ks < KC; ks += 32) {
            const int ko = ks + kg8 * 8;
            short8v a0 = *(const short8v*)&A[lidx(32 * wr + r16,      ko)];
            short8v a1 = *(const short8v*)&A[lidx(32 * wr + 16 + r16, ko)];
            short8v b0 = *(const short8v*)&B[lidx(32 * wc + r16,      ko)];
            short8v b1 = *(const short8v*)&B[lidx(32 * wc + 16 + r16, ko)];
            acc[0][0] = __builtin_amdgcn_mfma_f32_16x16x32_bf16(a0, b0, acc[0][0], 0, 0, 0);
            acc[0][1] = __builtin_amdgcn_mfma_f32_16x16x32_bf16(a0, b1, acc[0][1], 0, 0, 0);
            acc[1][0] = __builtin_amdgcn_mfma_f32_16x16x32_bf16(a1, b0, acc[1][0], 0, 0, 0);
            acc[1][1] = __builtin_amdgcn_mfma_f32_16x16x32_bf16(a1, b1, acc[1][1], 0, 0, 0);
        }
    };

    short8v ra[2], rb[2], sa[2], sb[2];
    load_chunk(0, ra, rb);
    load_chunk(1, sa, sb);

    // epilogue prefetch
    const int jj = tid & 15;
    const int row0 = tid >> 4;
    const f32x4 bp = *(const f32x4*)&biasP[jt * 64 + jj * 4];
    ushort4v xp[4]; float cp[4];
    #pragma unroll
    for (int u = 0; u < 4; ++u) {
        int batch = bx * 64 + row0 + 16 * u;
        xp[u] = __builtin_nontemporal_load(
            (const ushort4v*)&xprojP[((size_t)t * BT + batch) * G4 + jt * 64 + jj * 4]);
        cp[u] = cbuf[batch * HH + jt * 16 + jj];
    }

    write_chunk(As0, Bs0, ra, rb);
    __syncthreads();

    for (int ch = 0; ch < NCHH; ch += 2) {
        if (ch + 2 < NCHH) load_chunk(ch + 2, ra, rb);
        write_chunk(As1, Bs1, sa, sb);       // chunk ch+1 (NCHH even)
        compute(As0, Bs0);                    // chunk ch
        __syncthreads();
        if (ch + 3 < NCHH) load_chunk(ch + 3, sa, sb);
        if (ch + 2 < NCHH) write_chunk(As0, Bs0, ra, rb);
        compute(As1, Bs1);                    // chunk ch+1
        __syncthreads();
    }

    // gate exchange (verified C/D mapping: row=(lane>>4)*4+reg, col=lane&15)
    #pragma unroll
    for (int i = 0; i < 2; ++i)
        #pragma unroll
        for (int j2 = 0; j2 < 2; ++j2)
            #pragma unroll
            for (int r = 0; r < 4; ++r) {
                int grow = (2 * wr + i) * 16 + kg8 * 4 + r;
                int gcol = (2 * wc + j2) * 16 + r16;
                gbuf[grow * 65 + gcol] = acc[i][j2][r];
            }
    __syncthreads();

    #pragma unroll
    for (int u = 0; u < 4; ++u) {
        int row = row0 + 16 * u;
        int batch = bx * 64 + row;
        int j = jt * 16 + jj;
        float gi = gbuf[row * 65 +      jj] + bp[0] + bf2f(xp[u][0]);
        float gf = gbuf[row * 65 + 16 + jj] + bp[1] + bf2f(xp[u][1]);
        float gg = gbuf[row * 65 + 32 + jj] + bp[2] + bf2f(xp[u][2]);
        float go = gbuf[row * 65 + 48 + jj] + bp[3] + bf2f(xp[u][3]);
        float cn = sigm(gf) * cp[u] + sigm(gi) * tanh_f(gg);
        float hn = sigm(go) * tanh_f(cn);
        cbuf[batch * HH + j] = cn;
        unsigned short hi = f2bf(hn);
        hhi_out[batch * HH + j] = hi;
        hlo_out[batch * HH + j] = f2bf(hn - bf2f(hi));
    }
}

// ---------------------------------------------------------------------------
__global__ __launch_bounds__(64) void finalize(const unsigned short* __restrict__ hhi,
                                               const unsigned short* __restrict__ hlo,
                                               float* __restrict__ out)
{
    const int b = blockIdx.x;       // 0..255
    const int lane = threadIdx.x;   // 64
    float s = 0.0f;
    for (int j = lane; j < HH; j += 64) {
        float ha = bf2f(hhi[b * HH + j]) + bf2f(hlo[b * HH + j]);
        float hb = bf2f(hhi[(b + BB) * HH + j]) + bf2f(hlo[(b + BB) * HH + j]);
        s += fabsf(ha - hb);
    }
    #pragma unroll
    for (int off = 32; off > 0; off >>= 1) s += __shfl_down(s, off);
    if (lane == 0) out[b] = expf(-s);
}

// ---------------------------------------------------------------------------
extern "C" void kernel_launch(void* const* d_in, const int* in_sizes, int n_in,
                              void* d_out, int out_size, void* d_ws, size_t ws_size,
                              hipStream_t stream)
{
    const int*   s1  = (const int*)d_in[0];
    const int*   s2  = (const int*)d_in[1];
    const float* emb = (const float*)d_in[2];
    const float* Wih = (const float*)d_in[3];
    const float* Whh = (const float*)d_in[4];
    const float* bih = (const float*)d_in[5];
    const float* bhh = (const float*)d_in[6];
    const float* h0a = (const float*)d_in[7];
    const float* c0a = (const float*)d_in[8];
    const float* h0b = (const float*)d_in[9];
    const float* c0b = (const float*)d_in[10];
    float* out = (float*)d_out;

    char* ws = (char*)d_ws;
    size_t off = 0;
    unsigned short* WcatP = (unsigned short*)(ws + off); off += (size_t)G4 * KW * 2;   // 2 MB
    unsigned short* WihP  = (unsigned short*)(ws + off); off += (size_t)G4 * KX * 2;   // 1.3 MB
    float* biasP          = (float*)(ws + off);          off += (size_t)G4 * 4;
    unsigned short* hhi0  = (unsigned short*)(ws + off); off += (size_t)BT * HH * 2;
    unsigned short* hhi1  = (unsigned short*)(ws + off); off += (size_t)BT * HH * 2;
    unsigned short* hlo0  = (unsigned short*)(ws + off); off += (size_t)BT * HH * 2;
    unsigned short* hlo1  = (unsigned short*)(ws + off); off += (size_t)BT * HH * 2;
    float* cbuf           = (float*)(ws + off);          off += (size_t)BT * HH * 4;   // 1 MB
    unsigned short* Xbf   = (unsigned short*)(ws + off); off += (size_t)TT * BT * KX * 2; // 21 MB
    unsigned short* xprojP= (unsigned short*)(ws + off); off += (size_t)TT * BT * G4 * 2; // 134 MB

    prep_w<<<G4, 256, 0, stream>>>(Wih, Whh, bih, bhh, WcatP, WihP, biasP);
    prep_h<<<BT, 256, 0, stream>>>(h0a, c0a, h0b, c0b, hhi0, hlo0, cbuf);
    gather_x<<<(TT * BT * 40) / 256, 256, 0, stream>>>(s1, s2, emb, Xbf);
    gemm_x<<<512 * 32, 256, 0, stream>>>(Xbf, WihP, xprojP);

    unsigned short* hhi[2] = { hhi0, hhi1 };
    unsigned short* hlo[2] = { hlo0, hlo1 };
    for (int t = 0; t < TT; ++t) {
        int pi = t & 1, po = pi ^ 1;
        lstm_step<<<256, 256, 0, stream>>>(WcatP, biasP, xprojP,
                                           hhi[pi], hlo[pi], cbuf,
                                           hhi[po], hlo[po], t);
    }
    // t=63 (odd) writes buffer 0
    finalize<<<BB, 64, 0, stream>>>(hhi0, hlo0, out);
}